// Round 3
// baseline (763.956 us; speedup 1.0000x reference)
//
#include <hip/hip_runtime.h>
#include <cstdint>

typedef __bf16 bf16x8 __attribute__((ext_vector_type(8)));
typedef float floatx4 __attribute__((ext_vector_type(4)));
typedef unsigned short u16;
typedef unsigned int u32;

#define SCALE2 0.1275434297677098f   // (1/sqrt(128)) * log2(e)
#define CLIP2  144.26950408889634f   // 100 * log2(e)

__device__ __forceinline__ u16 f2bf(float f) {
  union { float f; u32 i; } v; v.f = f;
  u32 r = v.i + 0x7fffu + ((v.i >> 16) & 1u);
  return (u16)(r >> 16);
}

// async global->LDS 16B: LDS dest is wave-uniform base + lane*16
__device__ __forceinline__ void gll16(const void* g, void* l) {
  __builtin_amdgcn_global_load_lds(
      (const __attribute__((address_space(1))) u32*)g,
      (__attribute__((address_space(3))) u32*)l, 16, 0, 0);
}

// ---------------- fp32 -> bf16 elementwise convert ---------------------------
__global__ __launch_bounds__(256) void convert_bf16(
    const float* __restrict__ src, u16* __restrict__ dst, int n4) {
  int i = blockIdx.x * 256 + threadIdx.x;
  if (i >= n4) return;
  float4 v = ((const float4*)src)[i];
  ushort4 o;
  o.x = f2bf(v.x); o.y = f2bf(v.y); o.z = f2bf(v.z); o.w = f2bf(v.w);
  ((ushort4*)dst)[i] = o;
}

// ---------------- transpose (fp32 in, bf16 out), up-to-3 concat sources ------
__global__ __launch_bounds__(256) void transpose_cat(
    const float* __restrict__ W0, const float* __restrict__ W1,
    const float* __restrict__ W2,
    int n1, int n2, int ld0, int ld1, int ld2, int K, u16* __restrict__ Bt) {
  __shared__ u16 tile[32][33];
  const int k0 = blockIdx.x * 32, n0 = blockIdx.y * 32;
  const float* src; int ld, nb;
  if (n0 < n1)      { src = W0; ld = ld0; nb = n0; }
  else if (n0 < n2) { src = W1; ld = ld1; nb = n0 - n1; }
  else              { src = W2; ld = ld2; nb = n0 - n2; }
  const int tx = threadIdx.x, ty = threadIdx.y;
#pragma unroll
  for (int i = 0; i < 4; i++) {
    int k = ty + i * 8;
    tile[k][tx] = f2bf(src[(size_t)(k0 + k) * ld + nb + tx]);
  }
  __syncthreads();
#pragma unroll
  for (int i = 0; i < 4; i++) {
    int n = ty + i * 8;
    Bt[(size_t)(n0 + n) * K + k0 + tx] = tile[tx][n];
  }
}

// ---------------- GEMM: C[M,N] = A[M,K] @ Bt[N,K]^T (+bias) ------------------
// m97 pattern: 128x128 tile, BK=32, global_load_lds width-16, unpadded LDS.
template <int EPI>
__global__ __launch_bounds__(256) void gemm_bt(
    const u16* __restrict__ A, const u16* __restrict__ Bt,
    const float* __restrict__ bias0, const float* __restrict__ bias1,
    const float* __restrict__ bias2,
    u16* __restrict__ out0, u16* __restrict__ out1, u16* __restrict__ out2,
    float* __restrict__ outf,
    int M, int N, int K) {
  __shared__ u16 As[128][32];
  __shared__ u16 Bs[128][32];
  const int tid  = threadIdx.x;
  const int w    = tid >> 6, L = tid & 63, ln = L & 15, quad = L >> 4;
  const int m0   = blockIdx.y * 128, n0 = blockIdx.x * 128;
  const int mw   = (w & 1) * 64, nw = (w >> 1) * 64;
  // staging: wave w covers rows w*32..w*32+31 (2 calls of 16 rows each)
  const int sr = w * 32 + (L >> 2), sc = (L & 3) * 8;
  const u16* ga = &A [(size_t)(m0 + sr) * K + sc];
  const u16* gb = &Bt[(size_t)(n0 + sr) * K + sc];
  u16* la0 = &As[w * 32][0];
  u16* la1 = &As[w * 32 + 16][0];
  u16* lb0 = &Bs[w * 32][0];
  u16* lb1 = &Bs[w * 32 + 16][0];
  floatx4 acc[4][4] = {};

  for (int kt = 0; kt < K; kt += 32) {
    __syncthreads();
    gll16(ga + kt, la0);
    gll16(ga + (size_t)16 * K + kt, la1);
    gll16(gb + kt, lb0);
    gll16(gb + (size_t)16 * K + kt, lb1);
    __syncthreads();
    bf16x8 af[4], bf[4];
#pragma unroll
    for (int mb = 0; mb < 4; mb++) af[mb] = *(const bf16x8*)&As[mw + mb * 16 + ln][quad * 8];
#pragma unroll
    for (int nb = 0; nb < 4; nb++) bf[nb] = *(const bf16x8*)&Bs[nw + nb * 16 + ln][quad * 8];
#pragma unroll
    for (int mb = 0; mb < 4; mb++)
#pragma unroll
      for (int nb = 0; nb < 4; nb++)
        acc[mb][nb] = __builtin_amdgcn_mfma_f32_16x16x32_bf16(af[mb], bf[nb], acc[mb][nb], 0, 0, 0);
  }

#pragma unroll
  for (int mb = 0; mb < 4; mb++) {
#pragma unroll
    for (int nb = 0; nb < 4; nb++) {
#pragma unroll
      for (int r = 0; r < 4; r++) {
        const int m = m0 + mw + mb * 16 + quad * 4 + r;
        const int n = n0 + nw + nb * 16 + ln;
        float v = acc[mb][nb][r];
        if constexpr (EPI == 0) {
          if (n < 2048) {            // Q: bf16 [4096][2048]
            v += bias0[n];
            out0[(size_t)m * 2048 + n] = f2bf(v);
          } else if (n < 2304) {     // K: bf16 [4096][256]
            const int j = n - 2048;
            v += bias1[j];
            out1[(size_t)m * 256 + j] = f2bf(v);
          } else {                   // V transposed: Vt[(b*2+hk)*128+d][t]
            const int j = n - 2304;  // j = hk*128 + d
            v += bias2[j];
            const int b = m >> 11, t = m & 2047;
            out2[((size_t)(b * 256 + j)) * 2048 + t] = f2bf(v);
          }
        } else {
          v += bias0[n];
          outf[(size_t)m * (size_t)N + n] = v;
        }
      }
    }
  }
}

// ---------------- flash attention (barrier-free) -----------------------------
// Grid (T/64, H, B); 256 threads = 4 waves; wave w owns query rows [w*16,+16).
// K/V fragments read DIRECTLY from global (L2-resident); LDS = per-wave Ps only.
// Softmax in exp2 domain (scale/clip pre-multiplied by log2e).
__global__ __launch_bounds__(256) void attn_kernel(
    const u16* __restrict__ Q, const u16* __restrict__ K,
    const u16* __restrict__ Vt, u16* __restrict__ O) {
  __shared__ u16 Ps[4][16][72];   // per-wave P round-trip (C-layout -> A-layout)
  const int tid = threadIdx.x;
  const int w = tid >> 6, L = tid & 63, ln = L & 15, quad = L >> 4;
  const int qt = blockIdx.x, h = blockIdx.y, b = blockIdx.z;
  const int hk = h >> 3;  // G = 8
  const size_t qrow0 = (size_t)b * 2048 + qt * 64 + w * 16;

  bf16x8 qf[4];
#pragma unroll
  for (int kc = 0; kc < 4; kc++)
    qf[kc] = *(const bf16x8*)&Q[(qrow0 + ln) * 2048 + h * 128 + kc * 32 + quad * 8];

  floatx4 o[8] = {};
  float mrow[4] = {-1e30f, -1e30f, -1e30f, -1e30f};
  float lrow[4] = {0.f, 0.f, 0.f, 0.f};
  const u16* Kbase = K + (size_t)b * 2048 * 256 + hk * 128;
  const u16* Vbase = Vt + (size_t)(b * 2 + hk) * 128 * 2048;

  for (int s0 = 0; s0 < 2048; s0 += 64) {
    // ---- S = Q K^T (K frags straight from global; keys nb*16+ln, feats kc*32+quad*8)
    floatx4 sf[4] = {};
#pragma unroll
    for (int kc = 0; kc < 4; kc++) {
#pragma unroll
      for (int nb = 0; nb < 4; nb++) {
        bf16x8 kf = *(const bf16x8*)&Kbase[(size_t)(s0 + nb * 16 + ln) * 256 + kc * 32 + quad * 8];
        sf[nb] = __builtin_amdgcn_mfma_f32_16x16x32_bf16(qf[kc], kf, sf[nb], 0, 0, 0);
      }
    }
#pragma unroll
    for (int nb = 0; nb < 4; nb++)
#pragma unroll
      for (int r = 0; r < 4; r++)
        sf[nb][r] = fminf(fmaxf(sf[nb][r] * SCALE2, -CLIP2), CLIP2);

    float alpha[4];
#pragma unroll
    for (int r = 0; r < 4; r++) {
      float mx = fmaxf(fmaxf(sf[0][r], sf[1][r]), fmaxf(sf[2][r], sf[3][r]));
#pragma unroll
      for (int off = 1; off < 16; off <<= 1) mx = fmaxf(mx, __shfl_xor(mx, off));
      float mn = fmaxf(mrow[r], mx);
      alpha[r] = exp2f(mrow[r] - mn);
      mrow[r] = mn;
      float s = 0.f;
#pragma unroll
      for (int nb = 0; nb < 4; nb++) {
        float p = exp2f(sf[nb][r] - mn);
        sf[nb][r] = p;
        s += p;
      }
#pragma unroll
      for (int off = 1; off < 16; off <<= 1) s += __shfl_xor(s, off);
      lrow[r] = lrow[r] * alpha[r] + s;
    }
#pragma unroll
    for (int nb = 0; nb < 8; nb++)
#pragma unroll
      for (int r = 0; r < 4; r++) o[nb][r] *= alpha[r];

    // P (C-layout in regs) -> per-wave LDS -> A-layout frags
#pragma unroll
    for (int nb = 0; nb < 4; nb++)
#pragma unroll
      for (int r = 0; r < 4; r++)
        Ps[w][quad * 4 + r][nb * 16 + ln] = f2bf(sf[nb][r]);
#pragma unroll
    for (int kc = 0; kc < 2; kc++) {
      bf16x8 pf = *(const bf16x8*)&Ps[w][ln][kc * 32 + quad * 8];
#pragma unroll
      for (int nb = 0; nb < 8; nb++) {
        bf16x8 vf = *(const bf16x8*)&Vbase[(size_t)(nb * 16 + ln) * 2048 + s0 + kc * 32 + quad * 8];
        o[nb] = __builtin_amdgcn_mfma_f32_16x16x32_bf16(pf, vf, o[nb], 0, 0, 0);
      }
    }
  }

#pragma unroll
  for (int r = 0; r < 4; r++) {
    float inv = 1.f / lrow[r];
    size_t row = qrow0 + quad * 4 + r;
#pragma unroll
    for (int nb = 0; nb < 8; nb++)
      O[row * 2048 + h * 128 + nb * 16 + ln] = f2bf(o[nb][r] * inv);
  }
}

extern "C" void kernel_launch(void* const* d_in, const int* in_sizes, int n_in,
                              void* d_out, int out_size, void* d_ws, size_t ws_size,
                              hipStream_t stream) {
  const float* x  = (const float*)d_in[0];
  const float* Wq = (const float*)d_in[1];
  const float* bq = (const float*)d_in[2];
  const float* Wk = (const float*)d_in[3];
  const float* bk = (const float*)d_in[4];
  const float* Wv = (const float*)d_in[5];
  const float* bv = (const float*)d_in[6];
  const float* Wo = (const float*)d_in[7];
  const float* bo = (const float*)d_in[8];
  float* out = (float*)d_out;

  // Workspace layout (bytes). xb is dead after the QKV GEMM, so Ob aliases it.
  char* ws = (char*)d_ws;
  u16* xb     = (u16*)(ws);                      // 4096*2048*2 = 16777216
  u16* Ob     = (u16*)(ws);                      // aliases xb (attn runs after gemm1)
  u16* Wqkv_t = (u16*)(ws + 16777216);           // 2560*2048*2 = 10485760
  u16* Wot    = (u16*)(ws + 27262976);           // 2048*2048*2 =  8388608
  u16* Qb     = (u16*)(ws + 35651584);           // 4096*2048*2 = 16777216
  u16* Kb     = (u16*)(ws + 52428800);           // 4096*256*2  =  2097152
  u16* Vtb    = (u16*)(ws + 54525952);           // 512*2048*2  =  2097152
  (void)in_sizes; (void)n_in; (void)out_size; (void)ws_size;

  convert_bf16<<<8192, 256, 0, stream>>>(x, xb, 2097152);

  transpose_cat<<<dim3(64, 80), dim3(32, 8), 0, stream>>>(
      Wq, Wk, Wv, 2048, 2304, 2048, 256, 256, 2048, Wqkv_t);
  transpose_cat<<<dim3(64, 64), dim3(32, 8), 0, stream>>>(
      Wo, Wo, Wo, 2048, 2048, 2048, 2048, 2048, 2048, Wot);

  gemm_bt<0><<<dim3(20, 32), 256, 0, stream>>>(
      xb, Wqkv_t, bq, bk, bv, Qb, Kb, Vtb, nullptr, 4096, 2560, 2048);

  attn_kernel<<<dim3(32, 16, 2), 256, 0, stream>>>(Qb, Kb, Vtb, Ob);

  gemm_bt<1><<<dim3(16, 32), 256, 0, stream>>>(
      Ob, Wot, bo, nullptr, nullptr, nullptr, nullptr, nullptr, out, 4096, 2048, 2048);
}

// Round 4
// 408.412 us; speedup vs baseline: 1.8706x; 1.8706x over previous
//
#include <hip/hip_runtime.h>
#include <cstdint>

typedef __bf16 bf16x8 __attribute__((ext_vector_type(8)));
typedef float floatx4 __attribute__((ext_vector_type(4)));
typedef unsigned short u16;
typedef unsigned int u32;

#define SCALE2 0.1275434297677098f   // (1/sqrt(128)) * log2(e)
#define CLIP2  144.26950408889634f   // 100 * log2(e)

__device__ __forceinline__ u16 f2bf(float f) {
  union { float f; u32 i; } v; v.f = f;
  u32 r = v.i + 0x7fffu + ((v.i >> 16) & 1u);
  return (u16)(r >> 16);
}

// async global->LDS 16B: per-lane global address, wave-uniform LDS base + lane*16
__device__ __forceinline__ void gll16(const void* g, void* l) {
  __builtin_amdgcn_global_load_lds(
      (const __attribute__((address_space(1))) u32*)g,
      (__attribute__((address_space(3))) u32*)l, 16, 0, 0);
}

// ---------------- fp32 -> bf16 elementwise convert ---------------------------
__global__ __launch_bounds__(256) void convert_bf16(
    const float* __restrict__ src, u16* __restrict__ dst, int n4) {
  int i = blockIdx.x * 256 + threadIdx.x;
  if (i >= n4) return;
  float4 v = ((const float4*)src)[i];
  ushort4 o;
  o.x = f2bf(v.x); o.y = f2bf(v.y); o.z = f2bf(v.z); o.w = f2bf(v.w);
  ((ushort4*)dst)[i] = o;
}

// ---------------- transpose (fp32 in, bf16 out), up-to-3 concat sources ------
__global__ __launch_bounds__(256) void transpose_cat(
    const float* __restrict__ W0, const float* __restrict__ W1,
    const float* __restrict__ W2,
    int n1, int n2, int ld0, int ld1, int ld2, int K, u16* __restrict__ Bt) {
  __shared__ u16 tile[32][33];
  const int k0 = blockIdx.x * 32, n0 = blockIdx.y * 32;
  const float* src; int ld, nb;
  if (n0 < n1)      { src = W0; ld = ld0; nb = n0; }
  else if (n0 < n2) { src = W1; ld = ld1; nb = n0 - n1; }
  else              { src = W2; ld = ld2; nb = n0 - n2; }
  const int tx = threadIdx.x, ty = threadIdx.y;
#pragma unroll
  for (int i = 0; i < 4; i++) {
    int k = ty + i * 8;
    tile[k][tx] = f2bf(src[(size_t)(k0 + k) * ld + nb + tx]);
  }
  __syncthreads();
#pragma unroll
  for (int i = 0; i < 4; i++) {
    int n = ty + i * 8;
    Bt[(size_t)(n0 + n) * K + k0 + tx] = tile[tx][n];
  }
}

// ---------------- GEMM: C[M,N] = A[M,K] @ Bt[N,K]^T (+bias) ------------------
// m97 pattern: 128x128 tile, BK=32, global_load_lds width-16, unpadded LDS.
template <int EPI>
__global__ __launch_bounds__(256) void gemm_bt(
    const u16* __restrict__ A, const u16* __restrict__ Bt,
    const float* __restrict__ bias0, const float* __restrict__ bias1,
    const float* __restrict__ bias2,
    u16* __restrict__ out0, u16* __restrict__ out1, u16* __restrict__ out2,
    float* __restrict__ outf,
    int M, int N, int K) {
  __shared__ u16 As[128][32];
  __shared__ u16 Bs[128][32];
  const int tid  = threadIdx.x;
  const int w    = tid >> 6, L = tid & 63, ln = L & 15, quad = L >> 4;
  const int m0   = blockIdx.y * 128, n0 = blockIdx.x * 128;
  const int mw   = (w & 1) * 64, nw = (w >> 1) * 64;
  const int sr = w * 32 + (L >> 2), sc = (L & 3) * 8;
  const u16* ga = &A [(size_t)(m0 + sr) * K + sc];
  const u16* gb = &Bt[(size_t)(n0 + sr) * K + sc];
  u16* la0 = &As[w * 32][0];
  u16* la1 = &As[w * 32 + 16][0];
  u16* lb0 = &Bs[w * 32][0];
  u16* lb1 = &Bs[w * 32 + 16][0];
  floatx4 acc[4][4] = {};

  for (int kt = 0; kt < K; kt += 32) {
    __syncthreads();
    gll16(ga + kt, la0);
    gll16(ga + (size_t)16 * K + kt, la1);
    gll16(gb + kt, lb0);
    gll16(gb + (size_t)16 * K + kt, lb1);
    __syncthreads();
    bf16x8 af[4], bf[4];
#pragma unroll
    for (int mb = 0; mb < 4; mb++) af[mb] = *(const bf16x8*)&As[mw + mb * 16 + ln][quad * 8];
#pragma unroll
    for (int nb = 0; nb < 4; nb++) bf[nb] = *(const bf16x8*)&Bs[nw + nb * 16 + ln][quad * 8];
#pragma unroll
    for (int mb = 0; mb < 4; mb++)
#pragma unroll
      for (int nb = 0; nb < 4; nb++)
        acc[mb][nb] = __builtin_amdgcn_mfma_f32_16x16x32_bf16(af[mb], bf[nb], acc[mb][nb], 0, 0, 0);
  }

#pragma unroll
  for (int mb = 0; mb < 4; mb++) {
#pragma unroll
    for (int nb = 0; nb < 4; nb++) {
#pragma unroll
      for (int r = 0; r < 4; r++) {
        const int m = m0 + mw + mb * 16 + quad * 4 + r;
        const int n = n0 + nw + nb * 16 + ln;
        float v = acc[mb][nb][r];
        if constexpr (EPI == 0) {
          if (n < 2048) {            // Q: bf16 [4096][2048]
            v += bias0[n];
            out0[(size_t)m * 2048 + n] = f2bf(v);
          } else if (n < 2304) {     // K: bf16 [4096][256]
            const int j = n - 2048;
            v += bias1[j];
            out1[(size_t)m * 256 + j] = f2bf(v);
          } else {                   // V transposed: Vt[(b*2+hk)*128+d][t]
            const int j = n - 2304;  // j = hk*128 + d
            v += bias2[j];
            const int b = m >> 11, t = m & 2047;
            out2[((size_t)(b * 256 + j)) * 2048 + t] = f2bf(v);
          }
        } else {
          v += bias0[n];
          outf[(size_t)m * (size_t)N + n] = v;
        }
      }
    }
  }
}

// ---------------- flash attention -------------------------------------------
// Grid (T/128, H, B); 512 threads = 8 waves; wave w owns query rows [w*16,+16).
// K/V tiles staged to LDS in FRAGMENT ORDER via global_load_lds:
//   K frag f=(kc*4+nb)  at Ksh + f*512 u16;  lane L holds K[s0+nb*16+(L&15)][kc*32+(L>>4)*8 ..+8]
//   V frag f=(kc*8+nb)  at Vsh + f*512 u16;  lane L holds Vt[nb*16+(L&15)][s0+kc*32+(L>>4)*8 ..+8]
// Frag read-back = ds_read_b128 at base + L*16 (conflict-free).
__global__ __launch_bounds__(512) void attn_kernel(
    const u16* __restrict__ Q, const u16* __restrict__ K,
    const u16* __restrict__ Vt, u16* __restrict__ O) {
  __shared__ u16 Ksh[16 * 512];   // 16 KB
  __shared__ u16 Vsh[16 * 512];   // 16 KB
  __shared__ u16 Ps[8][16][72];   // per-wave P round-trip (C-layout -> A-layout)
  const int tid = threadIdx.x;
  const int w = tid >> 6, L = tid & 63, ln = L & 15, quad = L >> 4;
  const int qt = blockIdx.x, h = blockIdx.y, b = blockIdx.z;
  const int hk = h >> 3;  // G = 8
  const size_t qrow0 = (size_t)b * 2048 + qt * 128 + w * 16;

  const u16* Kbase = K + (size_t)b * 2048 * 256 + hk * 128;
  const u16* Vbase = Vt + (size_t)(b * 2 + hk) * 128 * 2048;

  // staging assignment: wave w stages K frags {2w,2w+1} and V frags {2w,2w+1}
  const int fk0 = w * 2;
  const int kkc0 = fk0 >> 2, knb0 = fk0 & 3;
  const int kkc1 = (fk0 + 1) >> 2, knb1 = (fk0 + 1) & 3;
  const int vkc0 = fk0 >> 3, vnb0 = fk0 & 7;
  const int vkc1 = (fk0 + 1) >> 3, vnb1 = (fk0 + 1) & 7;
  const u16* gK0 = Kbase + (size_t)(knb0 * 16 + ln) * 256 + kkc0 * 32 + quad * 8;
  const u16* gK1 = Kbase + (size_t)(knb1 * 16 + ln) * 256 + kkc1 * 32 + quad * 8;
  const u16* gV0 = Vbase + (size_t)(vnb0 * 16 + ln) * 2048 + vkc0 * 32 + quad * 8;
  const u16* gV1 = Vbase + (size_t)(vnb1 * 16 + ln) * 2048 + vkc1 * 32 + quad * 8;
  u16* lK0 = &Ksh[(size_t)fk0 * 512];
  u16* lK1 = &Ksh[(size_t)(fk0 + 1) * 512];
  u16* lV0 = &Vsh[(size_t)fk0 * 512];
  u16* lV1 = &Vsh[(size_t)(fk0 + 1) * 512];

  bf16x8 qf[4];
#pragma unroll
  for (int kc = 0; kc < 4; kc++)
    qf[kc] = *(const bf16x8*)&Q[(qrow0 + ln) * 2048 + h * 128 + kc * 32 + quad * 8];

  floatx4 o[8] = {};
  float mrow[4] = {-1e30f, -1e30f, -1e30f, -1e30f};
  float lrow[4] = {0.f, 0.f, 0.f, 0.f};

  for (int s0 = 0; s0 < 2048; s0 += 64) {
    __syncthreads();   // prior iter's frag reads complete before overwrite
    gll16(gK0 + (size_t)s0 * 256, lK0);
    gll16(gK1 + (size_t)s0 * 256, lK1);
    gll16(gV0 + s0, lV0);
    gll16(gV1 + s0, lV1);
    __syncthreads();   // staging visible to all waves

    // ---- S = Q K^T
    floatx4 sf[4] = {};
#pragma unroll
    for (int kc = 0; kc < 4; kc++) {
#pragma unroll
      for (int nb = 0; nb < 4; nb++) {
        bf16x8 kf = *(const bf16x8*)&Ksh[(size_t)(kc * 4 + nb) * 512 + L * 8];
        sf[nb] = __builtin_amdgcn_mfma_f32_16x16x32_bf16(qf[kc], kf, sf[nb], 0, 0, 0);
      }
    }
#pragma unroll
    for (int nb = 0; nb < 4; nb++)
#pragma unroll
      for (int r = 0; r < 4; r++)
        sf[nb][r] = fminf(fmaxf(sf[nb][r] * SCALE2, -CLIP2), CLIP2);

    float alpha[4];
#pragma unroll
    for (int r = 0; r < 4; r++) {
      float mx = fmaxf(fmaxf(sf[0][r], sf[1][r]), fmaxf(sf[2][r], sf[3][r]));
#pragma unroll
      for (int off = 1; off < 16; off <<= 1) mx = fmaxf(mx, __shfl_xor(mx, off));
      float mn = fmaxf(mrow[r], mx);
      alpha[r] = exp2f(mrow[r] - mn);
      mrow[r] = mn;
      float s = 0.f;
#pragma unroll
      for (int nb = 0; nb < 4; nb++) {
        float p = exp2f(sf[nb][r] - mn);
        sf[nb][r] = p;
        s += p;
      }
#pragma unroll
      for (int off = 1; off < 16; off <<= 1) s += __shfl_xor(s, off);
      lrow[r] = lrow[r] * alpha[r] + s;
    }
#pragma unroll
    for (int nb = 0; nb < 8; nb++)
#pragma unroll
      for (int r = 0; r < 4; r++) o[nb][r] *= alpha[r];

    // P (C-layout in regs) -> per-wave LDS -> A-layout frags
#pragma unroll
    for (int nb = 0; nb < 4; nb++)
#pragma unroll
      for (int r = 0; r < 4; r++)
        Ps[w][quad * 4 + r][nb * 16 + ln] = f2bf(sf[nb][r]);
#pragma unroll
    for (int kc = 0; kc < 2; kc++) {
      bf16x8 pf = *(const bf16x8*)&Ps[w][ln][kc * 32 + quad * 8];
#pragma unroll
      for (int nb = 0; nb < 8; nb++) {
        bf16x8 vf = *(const bf16x8*)&Vsh[(size_t)(kc * 8 + nb) * 512 + L * 8];
        o[nb] = __builtin_amdgcn_mfma_f32_16x16x32_bf16(pf, vf, o[nb], 0, 0, 0);
      }
    }
  }

#pragma unroll
  for (int r = 0; r < 4; r++) {
    float inv = 1.f / lrow[r];
    size_t row = qrow0 + quad * 4 + r;
#pragma unroll
    for (int nb = 0; nb < 8; nb++)
      O[row * 2048 + h * 128 + nb * 16 + ln] = f2bf(o[nb][r] * inv);
  }
}

extern "C" void kernel_launch(void* const* d_in, const int* in_sizes, int n_in,
                              void* d_out, int out_size, void* d_ws, size_t ws_size,
                              hipStream_t stream) {
  const float* x  = (const float*)d_in[0];
  const float* Wq = (const float*)d_in[1];
  const float* bq = (const float*)d_in[2];
  const float* Wk = (const float*)d_in[3];
  const float* bk = (const float*)d_in[4];
  const float* Wv = (const float*)d_in[5];
  const float* bv = (const float*)d_in[6];
  const float* Wo = (const float*)d_in[7];
  const float* bo = (const float*)d_in[8];
  float* out = (float*)d_out;

  // Workspace layout (bytes). xb is dead after the QKV GEMM, so Ob aliases it.
  char* ws = (char*)d_ws;
  u16* xb     = (u16*)(ws);                      // 4096*2048*2 = 16777216
  u16* Ob     = (u16*)(ws);                      // aliases xb (attn runs after gemm1)
  u16* Wqkv_t = (u16*)(ws + 16777216);           // 2560*2048*2 = 10485760
  u16* Wot    = (u16*)(ws + 27262976);           // 2048*2048*2 =  8388608
  u16* Qb     = (u16*)(ws + 35651584);           // 4096*2048*2 = 16777216
  u16* Kb     = (u16*)(ws + 52428800);           // 4096*256*2  =  2097152
  u16* Vtb    = (u16*)(ws + 54525952);           // 512*2048*2  =  2097152
  (void)in_sizes; (void)n_in; (void)out_size; (void)ws_size;

  convert_bf16<<<8192, 256, 0, stream>>>(x, xb, 2097152);

  transpose_cat<<<dim3(64, 80), dim3(32, 8), 0, stream>>>(
      Wq, Wk, Wv, 2048, 2304, 2048, 256, 256, 2048, Wqkv_t);
  transpose_cat<<<dim3(64, 64), dim3(32, 8), 0, stream>>>(
      Wo, Wo, Wo, 2048, 2048, 2048, 2048, 2048, 2048, Wot);

  gemm_bt<0><<<dim3(20, 32), 256, 0, stream>>>(
      xb, Wqkv_t, bq, bk, bv, Qb, Kb, Vtb, nullptr, 4096, 2560, 2048);

  attn_kernel<<<dim3(16, 16, 2), 512, 0, stream>>>(Qb, Kb, Vtb, Ob);

  gemm_bt<1><<<dim3(16, 32), 256, 0, stream>>>(
      Ob, Wot, bo, nullptr, nullptr, nullptr, nullptr, nullptr, out, 4096, 2048, 2048);
}

// Round 5
// 391.034 us; speedup vs baseline: 1.9537x; 1.0444x over previous
//
#include <hip/hip_runtime.h>
#include <cstdint>

typedef __bf16 bf16x8 __attribute__((ext_vector_type(8)));
typedef float floatx4 __attribute__((ext_vector_type(4)));
typedef unsigned short u16;
typedef unsigned int u32;

#define SCALE2 0.1275434297677098f   // (1/sqrt(128)) * log2(e)
#define CLIP2  144.26950408889634f   // 100 * log2(e)

__device__ __forceinline__ u16 f2bf(float f) {
  union { float f; u32 i; } v; v.f = f;
  u32 r = v.i + 0x7fffu + ((v.i >> 16) & 1u);
  return (u16)(r >> 16);
}

// async global->LDS 16B: per-lane global address, wave-uniform LDS base + lane*16
__device__ __forceinline__ void gll16(const void* g, void* l) {
  __builtin_amdgcn_global_load_lds(
      (const __attribute__((address_space(1))) u32*)g,
      (__attribute__((address_space(3))) u32*)l, 16, 0, 0);
}

// ---------------- fp32 -> bf16 elementwise convert ---------------------------
__global__ __launch_bounds__(256) void convert_bf16(
    const float* __restrict__ src, u16* __restrict__ dst, int n4) {
  int i = blockIdx.x * 256 + threadIdx.x;
  if (i >= n4) return;
  float4 v = ((const float4*)src)[i];
  ushort4 o;
  o.x = f2bf(v.x); o.y = f2bf(v.y); o.z = f2bf(v.z); o.w = f2bf(v.w);
  ((ushort4*)dst)[i] = o;
}

// ---------------- transpose (fp32 in, bf16 out), up-to-3 concat sources ------
__global__ __launch_bounds__(256) void transpose_cat(
    const float* __restrict__ W0, const float* __restrict__ W1,
    const float* __restrict__ W2,
    int n1, int n2, int ld0, int ld1, int ld2, int K, u16* __restrict__ Bt) {
  __shared__ u16 tile[32][33];
  const int k0 = blockIdx.x * 32, n0 = blockIdx.y * 32;
  const float* src; int ld, nb;
  if (n0 < n1)      { src = W0; ld = ld0; nb = n0; }
  else if (n0 < n2) { src = W1; ld = ld1; nb = n0 - n1; }
  else              { src = W2; ld = ld2; nb = n0 - n2; }
  const int tx = threadIdx.x, ty = threadIdx.y;
#pragma unroll
  for (int i = 0; i < 4; i++) {
    int k = ty + i * 8;
    tile[k][tx] = f2bf(src[(size_t)(k0 + k) * ld + nb + tx]);
  }
  __syncthreads();
#pragma unroll
  for (int i = 0; i < 4; i++) {
    int n = ty + i * 8;
    Bt[(size_t)(n0 + n) * K + k0 + tx] = tile[tx][n];
  }
}

// ---------------- GEMM: C[M,N] = A[M,K] @ Bt[N,K]^T (+bias) ------------------
// 128x128 tile, BK=64 (two k-half LDS planes keep 64B row stride -> 2-way-free
// banks and gll16 lane contiguity). global_load_lds width-16 staging.
// EPI 0: QKV scatter epilogue (Q pre-scaled by SCALE2). EPI 1: fp32 out + bias.
template <int EPI>
__global__ __launch_bounds__(256) void gemm_bt(
    const u16* __restrict__ A, const u16* __restrict__ Bt,
    const float* __restrict__ bias0, const float* __restrict__ bias1,
    const float* __restrict__ bias2,
    u16* __restrict__ out0, u16* __restrict__ out1, u16* __restrict__ out2,
    float* __restrict__ outf,
    int M, int N, int K) {
  __shared__ u16 As[2][128][32];
  __shared__ u16 Bs[2][128][32];
  const int tid  = threadIdx.x;
  const int w    = tid >> 6, L = tid & 63, ln = L & 15, quad = L >> 4;
  const int m0   = blockIdx.y * 128, n0 = blockIdx.x * 128;
  const int mw   = (w & 1) * 64, nw = (w >> 1) * 64;
  // staging: wave w covers rows w*32..+31; call = (16 rows, k-half)
  const int sr = w * 32 + (L >> 2), sc = (L & 3) * 8;
  const u16* ga = &A [(size_t)(m0 + sr) * K + sc];
  const u16* gb = &Bt[(size_t)(n0 + sr) * K + sc];
  floatx4 acc[4][4] = {};

  for (int kt = 0; kt < K; kt += 64) {
    __syncthreads();
#pragma unroll
    for (int p = 0; p < 2; p++) {
#pragma unroll
      for (int kh = 0; kh < 2; kh++) {
        gll16(ga + (size_t)(p * 16) * K + kt + kh * 32, &As[kh][w * 32 + p * 16][0]);
        gll16(gb + (size_t)(p * 16) * K + kt + kh * 32, &Bs[kh][w * 32 + p * 16][0]);
      }
    }
    __syncthreads();
#pragma unroll
    for (int kh = 0; kh < 2; kh++) {
      bf16x8 af[4], bf[4];
#pragma unroll
      for (int mb = 0; mb < 4; mb++) af[mb] = *(const bf16x8*)&As[kh][mw + mb * 16 + ln][quad * 8];
#pragma unroll
      for (int nb = 0; nb < 4; nb++) bf[nb] = *(const bf16x8*)&Bs[kh][nw + nb * 16 + ln][quad * 8];
#pragma unroll
      for (int mb = 0; mb < 4; mb++)
#pragma unroll
        for (int nb = 0; nb < 4; nb++)
          acc[mb][nb] = __builtin_amdgcn_mfma_f32_16x16x32_bf16(af[mb], bf[nb], acc[mb][nb], 0, 0, 0);
    }
  }

#pragma unroll
  for (int mb = 0; mb < 4; mb++) {
#pragma unroll
    for (int nb = 0; nb < 4; nb++) {
#pragma unroll
      for (int r = 0; r < 4; r++) {
        const int m = m0 + mw + mb * 16 + quad * 4 + r;
        const int n = n0 + nw + nb * 16 + ln;
        float v = acc[mb][nb][r];
        if constexpr (EPI == 0) {
          if (n < 2048) {            // Q: bf16, pre-scaled by SCALE2
            v = (v + bias0[n]) * SCALE2;
            out0[(size_t)m * 2048 + n] = f2bf(v);
          } else if (n < 2304) {     // K: bf16 [4096][256]
            const int j = n - 2048;
            v += bias1[j];
            out1[(size_t)m * 256 + j] = f2bf(v);
          } else {                   // V transposed: Vt[(b*2+hk)*128+d][t]
            const int j = n - 2304;  // j = hk*128 + d
            v += bias2[j];
            const int b = m >> 11, t = m & 2047;
            out2[((size_t)(b * 256 + j)) * 2048 + t] = f2bf(v);
          }
        } else {
          v += bias0[n];
          outf[(size_t)m * (size_t)N + n] = v;
        }
      }
    }
  }
}

// ---------------- flash attention -------------------------------------------
// Grid (T/128, H, B); 512 threads = 8 waves; wave w owns query rows [w*16,+16).
// K/V staged to LDS in FRAGMENT ORDER via global_load_lds (conflict-free b128
// read-back at base + L*16). Q pre-scaled by SCALE2 (exp2 softmax domain).
// Row-sum l computed by a 9th ones-column MFMA accumulator (o9).
__global__ __launch_bounds__(512) void attn_kernel(
    const u16* __restrict__ Q, const u16* __restrict__ K,
    const u16* __restrict__ Vt, u16* __restrict__ O) {
  __shared__ u16 Ksh[16 * 512];   // 16 KB
  __shared__ u16 Vsh[16 * 512];   // 16 KB
  __shared__ u16 Ps[8][16][72];   // per-wave P round-trip (C-layout -> A-layout)
  const int tid = threadIdx.x;
  const int w = tid >> 6, L = tid & 63, ln = L & 15, quad = L >> 4;
  const int qt = blockIdx.x, h = blockIdx.y, b = blockIdx.z;
  const int hk = h >> 3;  // G = 8
  const size_t qrow0 = (size_t)b * 2048 + qt * 128 + w * 16;

  const u16* Kbase = K + (size_t)b * 2048 * 256 + hk * 128;
  const u16* Vbase = Vt + (size_t)(b * 2 + hk) * 128 * 2048;

  // staging: wave w stages K frags {2w,2w+1} and V frags {2w,2w+1}
  const int fk0 = w * 2;
  const int kkc0 = fk0 >> 2, knb0 = fk0 & 3;
  const int kkc1 = (fk0 + 1) >> 2, knb1 = (fk0 + 1) & 3;
  const int vkc0 = fk0 >> 3, vnb0 = fk0 & 7;
  const int vkc1 = (fk0 + 1) >> 3, vnb1 = (fk0 + 1) & 7;
  const u16* gK0 = Kbase + (size_t)(knb0 * 16 + ln) * 256 + kkc0 * 32 + quad * 8;
  const u16* gK1 = Kbase + (size_t)(knb1 * 16 + ln) * 256 + kkc1 * 32 + quad * 8;
  const u16* gV0 = Vbase + (size_t)(vnb0 * 16 + ln) * 2048 + vkc0 * 32 + quad * 8;
  const u16* gV1 = Vbase + (size_t)(vnb1 * 16 + ln) * 2048 + vkc1 * 32 + quad * 8;
  u16* lK0 = &Ksh[(size_t)fk0 * 512];
  u16* lK1 = &Ksh[(size_t)(fk0 + 1) * 512];
  u16* lV0 = &Vsh[(size_t)fk0 * 512];
  u16* lV1 = &Vsh[(size_t)(fk0 + 1) * 512];

  bf16x8 qf[4];
#pragma unroll
  for (int kc = 0; kc < 4; kc++)
    qf[kc] = *(const bf16x8*)&Q[(qrow0 + ln) * 2048 + h * 128 + kc * 32 + quad * 8];

  bf16x8 ones;
#pragma unroll
  for (int j = 0; j < 8; j++) {
    union { u16 u; __bf16 bx; } c; c.u = 0x3F80;  // bf16 1.0
    ones[j] = c.bx;
  }

  floatx4 o[8] = {};
  floatx4 o9 = {0.f, 0.f, 0.f, 0.f};   // row-sum accumulator (P @ ones)
  float mrow[4] = {-1e30f, -1e30f, -1e30f, -1e30f};

  for (int s0 = 0; s0 < 2048; s0 += 64) {
    __syncthreads();   // prior iter's frag reads complete before overwrite
    gll16(gK0 + (size_t)s0 * 256, lK0);
    gll16(gK1 + (size_t)s0 * 256, lK1);
    gll16(gV0 + s0, lV0);
    gll16(gV1 + s0, lV1);
    __syncthreads();   // staging visible to all waves

    // ---- S = Q K^T (already in exp2 domain; Q pre-scaled)
    floatx4 sf[4] = {};
#pragma unroll
    for (int kc = 0; kc < 4; kc++) {
#pragma unroll
      for (int nb = 0; nb < 4; nb++) {
        bf16x8 kf = *(const bf16x8*)&Ksh[(size_t)(kc * 4 + nb) * 512 + L * 8];
        sf[nb] = __builtin_amdgcn_mfma_f32_16x16x32_bf16(qf[kc], kf, sf[nb], 0, 0, 0);
      }
    }
#pragma unroll
    for (int nb = 0; nb < 4; nb++)
#pragma unroll
      for (int r = 0; r < 4; r++)
        sf[nb][r] = __builtin_amdgcn_fmed3f(sf[nb][r], -CLIP2, CLIP2);

    // ---- online max, alpha
    float alpha[4];
#pragma unroll
    for (int r = 0; r < 4; r++) {
      float mx = fmaxf(fmaxf(sf[0][r], sf[1][r]), fmaxf(sf[2][r], sf[3][r]));
#pragma unroll
      for (int off = 1; off < 16; off <<= 1) mx = fmaxf(mx, __shfl_xor(mx, off));
      float mn = fmaxf(mrow[r], mx);
      alpha[r] = __builtin_amdgcn_exp2f(mrow[r] - mn);
      mrow[r] = mn;
    }
    // rescale only when some row max updated (wave-uniform test)
    unsigned long long nd = __ballot(alpha[0] < 1.f || alpha[1] < 1.f ||
                                     alpha[2] < 1.f || alpha[3] < 1.f);
    if (nd) {
#pragma unroll
      for (int nb = 0; nb < 8; nb++)
#pragma unroll
        for (int r = 0; r < 4; r++) o[nb][r] *= alpha[r];
#pragma unroll
      for (int r = 0; r < 4; r++) o9[r] *= alpha[r];
    }

    // ---- p = exp2(s - m), write to Ps (C-layout -> A-layout round-trip)
#pragma unroll
    for (int nb = 0; nb < 4; nb++)
#pragma unroll
      for (int r = 0; r < 4; r++) {
        float p = __builtin_amdgcn_exp2f(sf[nb][r] - mrow[r]);
        Ps[w][quad * 4 + r][nb * 16 + ln] = f2bf(p);
      }
#pragma unroll
    for (int kc = 0; kc < 2; kc++) {
      bf16x8 pf = *(const bf16x8*)&Ps[w][ln][kc * 32 + quad * 8];
#pragma unroll
      for (int nb = 0; nb < 8; nb++) {
        bf16x8 vf = *(const bf16x8*)&Vsh[(size_t)(kc * 8 + nb) * 512 + L * 8];
        o[nb] = __builtin_amdgcn_mfma_f32_16x16x32_bf16(pf, vf, o[nb], 0, 0, 0);
      }
      o9 = __builtin_amdgcn_mfma_f32_16x16x32_bf16(pf, ones, o9, 0, 0, 0);
    }
  }

#pragma unroll
  for (int r = 0; r < 4; r++) {
    float inv = 1.f / o9[r];
    size_t row = qrow0 + quad * 4 + r;
#pragma unroll
    for (int nb = 0; nb < 8; nb++)
      O[row * 2048 + h * 128 + nb * 16 + ln] = f2bf(o[nb][r] * inv);
  }
}

extern "C" void kernel_launch(void* const* d_in, const int* in_sizes, int n_in,
                              void* d_out, int out_size, void* d_ws, size_t ws_size,
                              hipStream_t stream) {
  const float* x  = (const float*)d_in[0];
  const float* Wq = (const float*)d_in[1];
  const float* bq = (const float*)d_in[2];
  const float* Wk = (const float*)d_in[3];
  const float* bk = (const float*)d_in[4];
  const float* Wv = (const float*)d_in[5];
  const float* bv = (const float*)d_in[6];
  const float* Wo = (const float*)d_in[7];
  const float* bo = (const float*)d_in[8];
  float* out = (float*)d_out;

  // Workspace layout (bytes). xb is dead after the QKV GEMM, so Ob aliases it.
  char* ws = (char*)d_ws;
  u16* xb     = (u16*)(ws);                      // 4096*2048*2 = 16777216
  u16* Ob     = (u16*)(ws);                      // aliases xb (attn runs after gemm1)
  u16* Wqkv_t = (u16*)(ws + 16777216);           // 2560*2048*2 = 10485760
  u16* Wot    = (u16*)(ws + 27262976);           // 2048*2048*2 =  8388608
  u16* Qb     = (u16*)(ws + 35651584);           // 4096*2048*2 = 16777216
  u16* Kb     = (u16*)(ws + 52428800);           // 4096*256*2  =  2097152
  u16* Vtb    = (u16*)(ws + 54525952);           // 512*2048*2  =  2097152
  (void)in_sizes; (void)n_in; (void)out_size; (void)ws_size;

  convert_bf16<<<8192, 256, 0, stream>>>(x, xb, 2097152);

  transpose_cat<<<dim3(64, 80), dim3(32, 8), 0, stream>>>(
      Wq, Wk, Wv, 2048, 2304, 2048, 256, 256, 2048, Wqkv_t);
  transpose_cat<<<dim3(64, 64), dim3(32, 8), 0, stream>>>(
      Wo, Wo, Wo, 2048, 2048, 2048, 2048, 2048, 2048, Wot);

  gemm_bt<0><<<dim3(20, 32), 256, 0, stream>>>(
      xb, Wqkv_t, bq, bk, bv, Qb, Kb, Vtb, nullptr, 4096, 2560, 2048);

  attn_kernel<<<dim3(16, 16, 2), 512, 0, stream>>>(Qb, Kb, Vtb, Ob);

  gemm_bt<1><<<dim3(16, 32), 256, 0, stream>>>(
      Ob, Wot, bo, nullptr, nullptr, nullptr, nullptr, nullptr, out, 4096, 2048, 2048);
}

// Round 6
// 389.382 us; speedup vs baseline: 1.9620x; 1.0042x over previous
//
#include <hip/hip_runtime.h>
#include <cstdint>

typedef __bf16 bf16x8 __attribute__((ext_vector_type(8)));
typedef float floatx4 __attribute__((ext_vector_type(4)));
typedef unsigned short u16;
typedef unsigned int u32;

#define SCALE2 0.1275434297677098f   // (1/sqrt(128)) * log2(e)
#define CLIP2  144.26950408889634f   // 100 * log2(e)

__device__ __forceinline__ u16 f2bf(float f) {
  union { float f; u32 i; } v; v.f = f;
  u32 r = v.i + 0x7fffu + ((v.i >> 16) & 1u);
  return (u16)(r >> 16);
}

// async global->LDS 16B: per-lane global address, wave-uniform LDS base + lane*16
__device__ __forceinline__ void gll16(const void* g, void* l) {
  __builtin_amdgcn_global_load_lds(
      (const __attribute__((address_space(1))) u32*)g,
      (__attribute__((address_space(3))) u32*)l, 16, 0, 0);
}

// ---------------- fp32 -> bf16 elementwise convert ---------------------------
__global__ __launch_bounds__(256) void convert_bf16(
    const float* __restrict__ src, u16* __restrict__ dst, int n4) {
  int i = blockIdx.x * 256 + threadIdx.x;
  if (i >= n4) return;
  float4 v = ((const float4*)src)[i];
  ushort4 o;
  o.x = f2bf(v.x); o.y = f2bf(v.y); o.z = f2bf(v.z); o.w = f2bf(v.w);
  ((ushort4*)dst)[i] = o;
}

// ---------------- transpose (fp32 in, bf16 out), up-to-3 concat sources ------
__global__ __launch_bounds__(256) void transpose_cat(
    const float* __restrict__ W0, const float* __restrict__ W1,
    const float* __restrict__ W2,
    int n1, int n2, int ld0, int ld1, int ld2, int K, u16* __restrict__ Bt) {
  __shared__ u16 tile[32][33];
  const int k0 = blockIdx.x * 32, n0 = blockIdx.y * 32;
  const float* src; int ld, nb;
  if (n0 < n1)      { src = W0; ld = ld0; nb = n0; }
  else if (n0 < n2) { src = W1; ld = ld1; nb = n0 - n1; }
  else              { src = W2; ld = ld2; nb = n0 - n2; }
  const int tx = threadIdx.x, ty = threadIdx.y;
#pragma unroll
  for (int i = 0; i < 4; i++) {
    int k = ty + i * 8;
    tile[k][tx] = f2bf(src[(size_t)(k0 + k) * ld + nb + tx]);
  }
  __syncthreads();
#pragma unroll
  for (int i = 0; i < 4; i++) {
    int n = ty + i * 8;
    Bt[(size_t)(n0 + n) * K + k0 + tx] = tile[tx][n];
  }
}

// ---------------- GEMM: C[M,N] = A[M,K] @ Bt[N,K]^T (+bias) ------------------
// In-block split-K: 512 threads = two 4-wave groups; group g computes the same
// 128x128 C-tile over K-half g (BK=32, m97-style gll16 staging, per-group LDS
// planes), then group 1 spills acc through LDS and group 0 combines+epilogues.
// 16 waves/CU at VGPR<=128 (launch_bounds(512,4)).
template <int EPI>
__global__ __launch_bounds__(512, 4) void gemm_bt(
    const u16* __restrict__ A, const u16* __restrict__ Bt,
    const float* __restrict__ bias0, const float* __restrict__ bias1,
    const float* __restrict__ bias2,
    u16* __restrict__ out0, u16* __restrict__ out1, u16* __restrict__ out2,
    float* __restrict__ outf,
    int M, int N, int K) {
  __shared__ u16 As[2][128][32];   // [group][row][k] 16 KB
  __shared__ u16 Bs[2][128][32];   // 16 KB
  const int tid  = threadIdx.x;
  const int w8   = tid >> 6;       // 0..7
  const int g    = w8 >> 2;        // K-half group
  const int w    = w8 & 3;         // wave within group
  const int L    = tid & 63, ln = L & 15, quad = L >> 4;
  const int m0   = blockIdx.y * 128, n0 = blockIdx.x * 128;
  const int mw   = (w & 1) * 64, nw = (w >> 1) * 64;
  const int sr   = w * 32 + (L >> 2), sc = (L & 3) * 8;
  const int Kh   = K >> 1, kbase = g * Kh;
  const u16* ga = &A [(size_t)(m0 + sr) * K + kbase + sc];
  const u16* gb = &Bt[(size_t)(n0 + sr) * K + kbase + sc];
  u16* la0 = &As[g][w * 32][0];
  u16* la1 = &As[g][w * 32 + 16][0];
  u16* lb0 = &Bs[g][w * 32][0];
  u16* lb1 = &Bs[g][w * 32 + 16][0];
  floatx4 acc[4][4] = {};

  for (int kt = 0; kt < Kh; kt += 32) {
    __syncthreads();
    gll16(ga + kt, la0);
    gll16(ga + (size_t)16 * K + kt, la1);
    gll16(gb + kt, lb0);
    gll16(gb + (size_t)16 * K + kt, lb1);
    __syncthreads();
    bf16x8 af[4], bf[4];
#pragma unroll
    for (int mb = 0; mb < 4; mb++) af[mb] = *(const bf16x8*)&As[g][mw + mb * 16 + ln][quad * 8];
#pragma unroll
    for (int nb = 0; nb < 4; nb++) bf[nb] = *(const bf16x8*)&Bs[g][nw + nb * 16 + ln][quad * 8];
#pragma unroll
    for (int mb = 0; mb < 4; mb++)
#pragma unroll
      for (int nb = 0; nb < 4; nb++)
        acc[mb][nb] = __builtin_amdgcn_mfma_f32_16x16x32_bf16(af[mb], bf[nb], acc[mb][nb], 0, 0, 0);
  }

  // ---- combine (group1 -> LDS -> group0) + epilogue, one mb-slice at a time
  floatx4* cbuf = (floatx4*)&As[0][0][0];   // 16 KB, aliases dead As
#pragma unroll
  for (int mb = 0; mb < 4; mb++) {
    __syncthreads();
    if (g == 1) {
#pragma unroll
      for (int nb = 0; nb < 4; nb++) cbuf[(w * 4 + nb) * 64 + L] = acc[mb][nb];
    }
    __syncthreads();
    if (g == 0) {
#pragma unroll
      for (int nb = 0; nb < 4; nb++) {
        floatx4 other = cbuf[(w * 4 + nb) * 64 + L];
#pragma unroll
        for (int r = 0; r < 4; r++) {
          const int m = m0 + mw + mb * 16 + quad * 4 + r;
          const int n = n0 + nw + nb * 16 + ln;
          float v = acc[mb][nb][r] + other[r];
          if constexpr (EPI == 0) {
            if (n < 2048) {            // Q: bf16, pre-scaled by SCALE2
              v = (v + bias0[n]) * SCALE2;
              out0[(size_t)m * 2048 + n] = f2bf(v);
            } else if (n < 2304) {     // K: bf16 [4096][256]
              const int j = n - 2048;
              v += bias1[j];
              out1[(size_t)m * 256 + j] = f2bf(v);
            } else {                   // V transposed: Vt[(b*2+hk)*128+d][t]
              const int j = n - 2304;  // j = hk*128 + d
              v += bias2[j];
              const int b = m >> 11, t = m & 2047;
              out2[((size_t)(b * 256 + j)) * 2048 + t] = f2bf(v);
            }
          } else {
            v += bias0[n];
            outf[(size_t)m * (size_t)N + n] = v;
          }
        }
      }
    }
  }
}

// ---------------- flash attention -------------------------------------------
// Grid (T/128, H, B); 512 threads = 8 waves; wave w owns query rows [w*16,+16).
// K/V staged to LDS in FRAGMENT ORDER via global_load_lds (conflict-free b128
// read-back at base + L*16). Q pre-scaled by SCALE2 (exp2 softmax domain).
// Row-sum l via a 9th ones-column MFMA accumulator (o9).
__global__ __launch_bounds__(512) void attn_kernel(
    const u16* __restrict__ Q, const u16* __restrict__ K,
    const u16* __restrict__ Vt, u16* __restrict__ O) {
  __shared__ u16 Ksh[16 * 512];   // 16 KB
  __shared__ u16 Vsh[16 * 512];   // 16 KB
  __shared__ u16 Ps[8][16][72];   // per-wave P round-trip (C-layout -> A-layout)
  const int tid = threadIdx.x;
  const int w = tid >> 6, L = tid & 63, ln = L & 15, quad = L >> 4;
  const int qt = blockIdx.x, h = blockIdx.y, b = blockIdx.z;
  const int hk = h >> 3;  // G = 8
  const size_t qrow0 = (size_t)b * 2048 + qt * 128 + w * 16;

  const u16* Kbase = K + (size_t)b * 2048 * 256 + hk * 128;
  const u16* Vbase = Vt + (size_t)(b * 2 + hk) * 128 * 2048;

  // staging: wave w stages K frags {2w,2w+1} and V frags {2w,2w+1}
  const int fk0 = w * 2;
  const int kkc0 = fk0 >> 2, knb0 = fk0 & 3;
  const int kkc1 = (fk0 + 1) >> 2, knb1 = (fk0 + 1) & 3;
  const int vkc0 = fk0 >> 3, vnb0 = fk0 & 7;
  const int vkc1 = (fk0 + 1) >> 3, vnb1 = (fk0 + 1) & 7;
  const u16* gK0 = Kbase + (size_t)(knb0 * 16 + ln) * 256 + kkc0 * 32 + quad * 8;
  const u16* gK1 = Kbase + (size_t)(knb1 * 16 + ln) * 256 + kkc1 * 32 + quad * 8;
  const u16* gV0 = Vbase + (size_t)(vnb0 * 16 + ln) * 2048 + vkc0 * 32 + quad * 8;
  const u16* gV1 = Vbase + (size_t)(vnb1 * 16 + ln) * 2048 + vkc1 * 32 + quad * 8;
  u16* lK0 = &Ksh[(size_t)fk0 * 512];
  u16* lK1 = &Ksh[(size_t)(fk0 + 1) * 512];
  u16* lV0 = &Vsh[(size_t)fk0 * 512];
  u16* lV1 = &Vsh[(size_t)(fk0 + 1) * 512];

  bf16x8 qf[4];
#pragma unroll
  for (int kc = 0; kc < 4; kc++)
    qf[kc] = *(const bf16x8*)&Q[(qrow0 + ln) * 2048 + h * 128 + kc * 32 + quad * 8];

  bf16x8 ones;
#pragma unroll
  for (int j = 0; j < 8; j++) {
    union { u16 u; __bf16 bx; } c; c.u = 0x3F80;  // bf16 1.0
    ones[j] = c.bx;
  }

  floatx4 o[8] = {};
  floatx4 o9 = {0.f, 0.f, 0.f, 0.f};   // row-sum accumulator (P @ ones)
  float mrow[4] = {-1e30f, -1e30f, -1e30f, -1e30f};

  for (int s0 = 0; s0 < 2048; s0 += 64) {
    __syncthreads();   // prior iter's frag reads complete before overwrite
    gll16(gK0 + (size_t)s0 * 256, lK0);
    gll16(gK1 + (size_t)s0 * 256, lK1);
    gll16(gV0 + s0, lV0);
    gll16(gV1 + s0, lV1);
    __syncthreads();   // staging visible to all waves

    // ---- S = Q K^T (already in exp2 domain; Q pre-scaled)
    floatx4 sf[4] = {};
#pragma unroll
    for (int kc = 0; kc < 4; kc++) {
#pragma unroll
      for (int nb = 0; nb < 4; nb++) {
        bf16x8 kf = *(const bf16x8*)&Ksh[(size_t)(kc * 4 + nb) * 512 + L * 8];
        sf[nb] = __builtin_amdgcn_mfma_f32_16x16x32_bf16(qf[kc], kf, sf[nb], 0, 0, 0);
      }
    }
#pragma unroll
    for (int nb = 0; nb < 4; nb++)
#pragma unroll
      for (int r = 0; r < 4; r++)
        sf[nb][r] = __builtin_amdgcn_fmed3f(sf[nb][r], -CLIP2, CLIP2);

    // ---- online max, alpha
    float alpha[4];
#pragma unroll
    for (int r = 0; r < 4; r++) {
      float mx = fmaxf(fmaxf(sf[0][r], sf[1][r]), fmaxf(sf[2][r], sf[3][r]));
#pragma unroll
      for (int off = 1; off < 16; off <<= 1) mx = fmaxf(mx, __shfl_xor(mx, off));
      float mn = fmaxf(mrow[r], mx);
      alpha[r] = __builtin_amdgcn_exp2f(mrow[r] - mn);
      mrow[r] = mn;
    }
    // rescale only when some row max updated (wave-uniform test)
    unsigned long long nd = __ballot(alpha[0] < 1.f || alpha[1] < 1.f ||
                                     alpha[2] < 1.f || alpha[3] < 1.f);
    if (nd) {
#pragma unroll
      for (int nb = 0; nb < 8; nb++)
#pragma unroll
        for (int r = 0; r < 4; r++) o[nb][r] *= alpha[r];
#pragma unroll
      for (int r = 0; r < 4; r++) o9[r] *= alpha[r];
    }

    // ---- p = exp2(s - m), write to Ps (C-layout -> A-layout round-trip)
#pragma unroll
    for (int nb = 0; nb < 4; nb++)
#pragma unroll
      for (int r = 0; r < 4; r++) {
        float p = __builtin_amdgcn_exp2f(sf[nb][r] - mrow[r]);
        Ps[w][quad * 4 + r][nb * 16 + ln] = f2bf(p);
      }
#pragma unroll
    for (int kc = 0; kc < 2; kc++) {
      bf16x8 pf = *(const bf16x8*)&Ps[w][ln][kc * 32 + quad * 8];
#pragma unroll
      for (int nb = 0; nb < 8; nb++) {
        bf16x8 vf = *(const bf16x8*)&Vsh[(size_t)(kc * 8 + nb) * 512 + L * 8];
        o[nb] = __builtin_amdgcn_mfma_f32_16x16x32_bf16(pf, vf, o[nb], 0, 0, 0);
      }
      o9 = __builtin_amdgcn_mfma_f32_16x16x32_bf16(pf, ones, o9, 0, 0, 0);
    }
  }

#pragma unroll
  for (int r = 0; r < 4; r++) {
    float inv = 1.f / o9[r];
    size_t row = qrow0 + quad * 4 + r;
#pragma unroll
    for (int nb = 0; nb < 8; nb++)
      O[row * 2048 + h * 128 + nb * 16 + ln] = f2bf(o[nb][r] * inv);
  }
}

extern "C" void kernel_launch(void* const* d_in, const int* in_sizes, int n_in,
                              void* d_out, int out_size, void* d_ws, size_t ws_size,
                              hipStream_t stream) {
  const float* x  = (const float*)d_in[0];
  const float* Wq = (const float*)d_in[1];
  const float* bq = (const float*)d_in[2];
  const float* Wk = (const float*)d_in[3];
  const float* bk = (const float*)d_in[4];
  const float* Wv = (const float*)d_in[5];
  const float* bv = (const float*)d_in[6];
  const float* Wo = (const float*)d_in[7];
  const float* bo = (const float*)d_in[8];
  float* out = (float*)d_out;

  // Workspace layout (bytes). xb is dead after the QKV GEMM, so Ob aliases it.
  char* ws = (char*)d_ws;
  u16* xb     = (u16*)(ws);                      // 4096*2048*2 = 16777216
  u16* Ob     = (u16*)(ws);                      // aliases xb (attn runs after gemm1)
  u16* Wqkv_t = (u16*)(ws + 16777216);           // 2560*2048*2 = 10485760
  u16* Wot    = (u16*)(ws + 27262976);           // 2048*2048*2 =  8388608
  u16* Qb     = (u16*)(ws + 35651584);           // 4096*2048*2 = 16777216
  u16* Kb     = (u16*)(ws + 52428800);           // 4096*256*2  =  2097152
  u16* Vtb    = (u16*)(ws + 54525952);           // 512*2048*2  =  2097152
  (void)in_sizes; (void)n_in; (void)out_size; (void)ws_size;

  convert_bf16<<<8192, 256, 0, stream>>>(x, xb, 2097152);

  transpose_cat<<<dim3(64, 80), dim3(32, 8), 0, stream>>>(
      Wq, Wk, Wv, 2048, 2304, 2048, 256, 256, 2048, Wqkv_t);
  transpose_cat<<<dim3(64, 64), dim3(32, 8), 0, stream>>>(
      Wo, Wo, Wo, 2048, 2048, 2048, 2048, 2048, 2048, Wot);

  gemm_bt<0><<<dim3(20, 32), 512, 0, stream>>>(
      xb, Wqkv_t, bq, bk, bv, Qb, Kb, Vtb, nullptr, 4096, 2560, 2048);

  attn_kernel<<<dim3(16, 16, 2), 512, 0, stream>>>(Qb, Kb, Vtb, Ob);

  gemm_bt<1><<<dim3(16, 32), 512, 0, stream>>>(
      Ob, Wot, bo, nullptr, nullptr, nullptr, nullptr, nullptr, out, 4096, 2048, 2048);
}

// Round 7
// 346.594 us; speedup vs baseline: 2.2042x; 1.1235x over previous
//
#include <hip/hip_runtime.h>
#include <cstdint>

typedef __bf16 bf16x8 __attribute__((ext_vector_type(8)));
typedef float floatx4 __attribute__((ext_vector_type(4)));
typedef unsigned short u16;
typedef unsigned int u32;

#define SCALE2 0.1275434297677098f   // (1/sqrt(128)) * log2(e)
#define CLIP2  144.26950408889634f   // 100 * log2(e)

__device__ __forceinline__ u16 f2bf(float f) {
  union { float f; u32 i; } v; v.f = f;
  u32 r = v.i + 0x7fffu + ((v.i >> 16) & 1u);
  return (u16)(r >> 16);
}

// async global->LDS 16B: per-lane global address, wave-uniform LDS base + lane*16
__device__ __forceinline__ void gll16(const void* g, void* l) {
  __builtin_amdgcn_global_load_lds(
      (const __attribute__((address_space(1))) u32*)g,
      (__attribute__((address_space(3))) u32*)l, 16, 0, 0);
}

// ---------------- fp32 -> bf16 elementwise convert ---------------------------
__global__ __launch_bounds__(256) void convert_bf16(
    const float* __restrict__ src, u16* __restrict__ dst, int n4) {
  int i = blockIdx.x * 256 + threadIdx.x;
  if (i >= n4) return;
  float4 v = ((const float4*)src)[i];
  ushort4 o;
  o.x = f2bf(v.x); o.y = f2bf(v.y); o.z = f2bf(v.z); o.w = f2bf(v.w);
  ((ushort4*)dst)[i] = o;
}

// ---------------- transpose (fp32 in, bf16 out), up-to-3 concat sources ------
__global__ __launch_bounds__(256) void transpose_cat(
    const float* __restrict__ W0, const float* __restrict__ W1,
    const float* __restrict__ W2,
    int n1, int n2, int ld0, int ld1, int ld2, int K, u16* __restrict__ Bt) {
  __shared__ u16 tile[32][33];
  const int k0 = blockIdx.x * 32, n0 = blockIdx.y * 32;
  const float* src; int ld, nb;
  if (n0 < n1)      { src = W0; ld = ld0; nb = n0; }
  else if (n0 < n2) { src = W1; ld = ld1; nb = n0 - n1; }
  else              { src = W2; ld = ld2; nb = n0 - n2; }
  const int tx = threadIdx.x, ty = threadIdx.y;
#pragma unroll
  for (int i = 0; i < 4; i++) {
    int k = ty + i * 8;
    tile[k][tx] = f2bf(src[(size_t)(k0 + k) * ld + nb + tx]);
  }
  __syncthreads();
#pragma unroll
  for (int i = 0; i < 4; i++) {
    int n = ty + i * 8;
    Bt[(size_t)(n0 + n) * K + k0 + tx] = tile[tx][n];
  }
}

// ---------------- GEMM: C[M,N] = A[M,K] @ Bt[N,K]^T (+bias) ------------------
// 128x128 tile, BK=32, double-buffered LDS, ONE barrier per K-iter: prefetch
// for tile i+1 issued right after barrier_i, drained at barrier_{i+1} (a full
// 16-MFMA block of overlap).
template <int EPI>
__global__ __launch_bounds__(256) void gemm_bt(
    const u16* __restrict__ A, const u16* __restrict__ Bt,
    const float* __restrict__ bias0, const float* __restrict__ bias1,
    const float* __restrict__ bias2,
    u16* __restrict__ out0, u16* __restrict__ out1, u16* __restrict__ out2,
    float* __restrict__ outf,
    int M, int N, int K) {
  __shared__ u16 As[2][128][32];
  __shared__ u16 Bs[2][128][32];
  const int tid  = threadIdx.x;
  const int w    = tid >> 6, L = tid & 63, ln = L & 15, quad = L >> 4;
  const int m0   = blockIdx.y * 128, n0 = blockIdx.x * 128;
  const int mw   = (w & 1) * 64, nw = (w >> 1) * 64;
  const int sr = w * 32 + (L >> 2), sc = (L & 3) * 8;
  const u16* ga = &A [(size_t)(m0 + sr) * K + sc];
  const u16* gb = &Bt[(size_t)(n0 + sr) * K + sc];
  floatx4 acc[4][4] = {};
  const int nk = K >> 5;

  // prologue: stage tile 0 into buffer 0
  gll16(ga, &As[0][w * 32][0]);
  gll16(ga + (size_t)16 * K, &As[0][w * 32 + 16][0]);
  gll16(gb, &Bs[0][w * 32][0]);
  gll16(gb + (size_t)16 * K, &Bs[0][w * 32 + 16][0]);

  for (int i = 0; i < nk; i++) {
    const int cur = i & 1;
    __syncthreads();   // staging of buf[cur] drained; reads of buf[cur^1] done
    if (i + 1 < nk) {
      const int kt = (i + 1) << 5;
      gll16(ga + kt, &As[cur ^ 1][w * 32][0]);
      gll16(ga + (size_t)16 * K + kt, &As[cur ^ 1][w * 32 + 16][0]);
      gll16(gb + kt, &Bs[cur ^ 1][w * 32][0]);
      gll16(gb + (size_t)16 * K + kt, &Bs[cur ^ 1][w * 32 + 16][0]);
    }
    bf16x8 af[4], bf[4];
#pragma unroll
    for (int mb = 0; mb < 4; mb++) af[mb] = *(const bf16x8*)&As[cur][mw + mb * 16 + ln][quad * 8];
#pragma unroll
    for (int nb = 0; nb < 4; nb++) bf[nb] = *(const bf16x8*)&Bs[cur][nw + nb * 16 + ln][quad * 8];
#pragma unroll
    for (int mb = 0; mb < 4; mb++)
#pragma unroll
      for (int nb = 0; nb < 4; nb++)
        acc[mb][nb] = __builtin_amdgcn_mfma_f32_16x16x32_bf16(af[mb], bf[nb], acc[mb][nb], 0, 0, 0);
  }

#pragma unroll
  for (int mb = 0; mb < 4; mb++) {
#pragma unroll
    for (int nb = 0; nb < 4; nb++) {
#pragma unroll
      for (int r = 0; r < 4; r++) {
        const int m = m0 + mw + mb * 16 + quad * 4 + r;
        const int n = n0 + nw + nb * 16 + ln;
        float v = acc[mb][nb][r];
        if constexpr (EPI == 0) {
          if (n < 2048) {            // Q: bf16, pre-scaled by SCALE2
            v = (v + bias0[n]) * SCALE2;
            out0[(size_t)m * 2048 + n] = f2bf(v);
          } else if (n < 2304) {     // K: bf16 [4096][256]
            const int j = n - 2048;
            v += bias1[j];
            out1[(size_t)m * 256 + j] = f2bf(v);
          } else {                   // V transposed: Vt[(b*2+hk)*128+d][t]
            const int j = n - 2304;  // j = hk*128 + d
            v += bias2[j];
            const int b = m >> 11, t = m & 2047;
            out2[((size_t)(b * 256 + j)) * 2048 + t] = f2bf(v);
          }
        } else {
          v += bias0[n];
          outf[(size_t)m * (size_t)N + n] = v;
        }
      }
    }
  }
}

// ---------------- flash attention (S^T form, dbuf K/V, no Ps LDS) ------------
// Grid (T/128, H, B); 512 threads = 8 waves; wave w owns query rows [w*16,+16).
// S^T = K·Q^T (operand swap; staging/fragments byte-identical to before).
// Softmax state per lane (qrow = ln). P^T(C-layout) -> PV B-operand via 16
// register shuffles. O^T = V^T·P^T. K/V double-buffered (64 KB exactly),
// ONE barrier per key-tile.
__global__ __launch_bounds__(512, 4) void attn_kernel(
    const u16* __restrict__ Q, const u16* __restrict__ K,
    const u16* __restrict__ Vt, u16* __restrict__ O) {
  __shared__ u16 Ksh[2][16 * 512];   // 32 KB
  __shared__ u16 Vsh[2][16 * 512];   // 32 KB
  const int tid = threadIdx.x;
  const int w = tid >> 6, L = tid & 63, ln = L & 15, quad = L >> 4;
  const int qt = blockIdx.x, h = blockIdx.y, b = blockIdx.z;
  const int hk = h >> 3;  // G = 8
  const size_t qrow0 = (size_t)b * 2048 + qt * 128 + w * 16;

  const u16* Kbase = K + (size_t)b * 2048 * 256 + hk * 128;
  const u16* Vbase = Vt + (size_t)(b * 2 + hk) * 128 * 2048;

  // staging: wave w stages K frags {2w,2w+1} and V frags {2w,2w+1}
  const int fk0 = w * 2;
  const int kkc0 = fk0 >> 2, knb0 = fk0 & 3;
  const int kkc1 = (fk0 + 1) >> 2, knb1 = (fk0 + 1) & 3;
  const int vkc0 = fk0 >> 3, vnb0 = fk0 & 7;
  const int vkc1 = (fk0 + 1) >> 3, vnb1 = (fk0 + 1) & 7;
  const u16* gK0 = Kbase + (size_t)(knb0 * 16 + ln) * 256 + kkc0 * 32 + quad * 8;
  const u16* gK1 = Kbase + (size_t)(knb1 * 16 + ln) * 256 + kkc1 * 32 + quad * 8;
  const u16* gV0 = Vbase + (size_t)(vnb0 * 16 + ln) * 2048 + vkc0 * 32 + quad * 8;
  const u16* gV1 = Vbase + (size_t)(vnb1 * 16 + ln) * 2048 + vkc1 * 32 + quad * 8;

  bf16x8 qf[4];   // B-operand: B[k=d][n=qrow=ln], stationary
#pragma unroll
  for (int kc = 0; kc < 4; kc++)
    qf[kc] = *(const bf16x8*)&Q[(qrow0 + ln) * 2048 + h * 128 + kc * 32 + quad * 8];

  floatx4 oT[8] = {};               // O^T: oT[nb][r] = O[qrow=ln][nb*16+quad*4+r]
  float mrow = -1e30f, lrow = 0.f;  // per-lane (qrow = ln)

  // prologue: stage tile 0 into buffer 0
  gll16(gK0, &Ksh[0][(size_t)fk0 * 512]);
  gll16(gK1, &Ksh[0][(size_t)(fk0 + 1) * 512]);
  gll16(gV0, &Vsh[0][(size_t)fk0 * 512]);
  gll16(gV1, &Vsh[0][(size_t)(fk0 + 1) * 512]);

  const int s0l = ((L & 16) << 1) + ln;   // (quad&1)*32 + ln
  const int s1l = s0l + 16;
  const bool hi = (L & 32) != 0;          // quad >> 1

  for (int i = 0; i < 32; i++) {
    const int cur = i & 1;
    __syncthreads();
    if (i < 31) {
      const int s0 = (i + 1) * 64;
      gll16(gK0 + (size_t)s0 * 256, &Ksh[cur ^ 1][(size_t)fk0 * 512]);
      gll16(gK1 + (size_t)s0 * 256, &Ksh[cur ^ 1][(size_t)(fk0 + 1) * 512]);
      gll16(gV0 + s0, &Vsh[cur ^ 1][(size_t)fk0 * 512]);
      gll16(gV1 + s0, &Vsh[cur ^ 1][(size_t)(fk0 + 1) * 512]);
    }

    // ---- S^T = K Q^T : sf[nb][r] = score(qrow=ln, key = i*64 + nb*16+quad*4+r)
    floatx4 sf[4] = {};
#pragma unroll
    for (int kc = 0; kc < 4; kc++) {
#pragma unroll
      for (int nb = 0; nb < 4; nb++) {
        bf16x8 kf = *(const bf16x8*)&Ksh[cur][(size_t)(kc * 4 + nb) * 512 + L * 8];
        sf[nb] = __builtin_amdgcn_mfma_f32_16x16x32_bf16(kf, qf[kc], sf[nb], 0, 0, 0);
      }
    }
#pragma unroll
    for (int nb = 0; nb < 4; nb++)
#pragma unroll
      for (int r = 0; r < 4; r++)
        sf[nb][r] = __builtin_amdgcn_fmed3f(sf[nb][r], -CLIP2, CLIP2);

    // ---- per-lane online max (reduce over quads only)
    float mx = sf[0][0];
#pragma unroll
    for (int nb = 0; nb < 4; nb++)
#pragma unroll
      for (int r = 0; r < 4; r++) mx = fmaxf(mx, sf[nb][r]);
    mx = fmaxf(mx, __shfl_xor(mx, 16));
    mx = fmaxf(mx, __shfl_xor(mx, 32));
    const float mn = fmaxf(mrow, mx);
    const float alpha = __builtin_amdgcn_exp2f(mrow - mn);
    mrow = mn;

    // ---- p = exp2(s - m); pack to bf16 pairs (P^T C-layout in regs)
    float s = 0.f;
    uint2 pk[4];
#pragma unroll
    for (int nb = 0; nb < 4; nb++) {
      float p0 = __builtin_amdgcn_exp2f(sf[nb][0] - mn);
      float p1 = __builtin_amdgcn_exp2f(sf[nb][1] - mn);
      float p2 = __builtin_amdgcn_exp2f(sf[nb][2] - mn);
      float p3 = __builtin_amdgcn_exp2f(sf[nb][3] - mn);
      s += (p0 + p1) + (p2 + p3);
      pk[nb].x = (u32)f2bf(p0) | ((u32)f2bf(p1) << 16);
      pk[nb].y = (u32)f2bf(p2) | ((u32)f2bf(p3) << 16);
    }
    s += __shfl_xor(s, 16);
    s += __shfl_xor(s, 32);
    lrow = lrow * alpha + s;

    if (__ballot(alpha < 1.f)) {
#pragma unroll
      for (int nb = 0; nb < 8; nb++)
#pragma unroll
        for (int r = 0; r < 4; r++) oT[nb][r] *= alpha;
    }

    // ---- build PV B-frags from pk via shuffles; O^T = V^T P^T
#pragma unroll
    for (int kc = 0; kc < 2; kc++) {
      u32 a0 = pk[2 * kc].x, a1 = pk[2 * kc].y;
      u32 b0 = pk[2 * kc + 1].x, b1 = pk[2 * kc + 1].y;
      u32 t00 = __shfl(a0, s0l), t01 = __shfl(a1, s0l);
      u32 t02 = __shfl(a0, s1l), t03 = __shfl(a1, s1l);
      u32 t10 = __shfl(b0, s0l), t11 = __shfl(b1, s0l);
      u32 t12 = __shfl(b0, s1l), t13 = __shfl(b1, s1l);
      union { u32 u[4]; bf16x8 v; } pb;
      pb.u[0] = hi ? t10 : t00;
      pb.u[1] = hi ? t11 : t01;
      pb.u[2] = hi ? t12 : t02;
      pb.u[3] = hi ? t13 : t03;
#pragma unroll
      for (int nb = 0; nb < 8; nb++) {
        bf16x8 vf = *(const bf16x8*)&Vsh[cur][(size_t)(kc * 8 + nb) * 512 + L * 8];
        oT[nb] = __builtin_amdgcn_mfma_f32_16x16x32_bf16(vf, pb.v, oT[nb], 0, 0, 0);
      }
    }
  }

  // ---- epilogue: O[qrow=ln][h*128 + nb*16 + quad*4 + r]
  const float inv = 1.f / lrow;
  u16* orow = O + (qrow0 + ln) * 2048 + h * 128;
#pragma unroll
  for (int nb = 0; nb < 8; nb++)
#pragma unroll
    for (int r = 0; r < 4; r++)
      orow[nb * 16 + quad * 4 + r] = f2bf(oT[nb][r] * inv);
}

extern "C" void kernel_launch(void* const* d_in, const int* in_sizes, int n_in,
                              void* d_out, int out_size, void* d_ws, size_t ws_size,
                              hipStream_t stream) {
  const float* x  = (const float*)d_in[0];
  const float* Wq = (const float*)d_in[1];
  const float* bq = (const float*)d_in[2];
  const float* Wk = (const float*)d_in[3];
  const float* bk = (const float*)d_in[4];
  const float* Wv = (const float*)d_in[5];
  const float* bv = (const float*)d_in[6];
  const float* Wo = (const float*)d_in[7];
  const float* bo = (const float*)d_in[8];
  float* out = (float*)d_out;

  // Workspace layout (bytes). xb is dead after the QKV GEMM, so Ob aliases it.
  char* ws = (char*)d_ws;
  u16* xb     = (u16*)(ws);                      // 4096*2048*2 = 16777216
  u16* Ob     = (u16*)(ws);                      // aliases xb (attn runs after gemm1)
  u16* Wqkv_t = (u16*)(ws + 16777216);           // 2560*2048*2 = 10485760
  u16* Wot    = (u16*)(ws + 27262976);           // 2048*2048*2 =  8388608
  u16* Qb     = (u16*)(ws + 35651584);           // 4096*2048*2 = 16777216
  u16* Kb     = (u16*)(ws + 52428800);           // 4096*256*2  =  2097152
  u16* Vtb    = (u16*)(ws + 54525952);           // 512*2048*2  =  2097152
  (void)in_sizes; (void)n_in; (void)out_size; (void)ws_size;

  convert_bf16<<<8192, 256, 0, stream>>>(x, xb, 2097152);

  transpose_cat<<<dim3(64, 80), dim3(32, 8), 0, stream>>>(
      Wq, Wk, Wv, 2048, 2304, 2048, 256, 256, 2048, Wqkv_t);
  transpose_cat<<<dim3(64, 64), dim3(32, 8), 0, stream>>>(
      Wo, Wo, Wo, 2048, 2048, 2048, 2048, 2048, 2048, Wot);

  gemm_bt<0><<<dim3(20, 32), 256, 0, stream>>>(
      xb, Wqkv_t, bq, bk, bv, Qb, Kb, Vtb, nullptr, 4096, 2560, 2048);

  attn_kernel<<<dim3(16, 16, 2), 512, 0, stream>>>(Qb, Kb, Vtb, Ob);

  gemm_bt<1><<<dim3(16, 32), 256, 0, stream>>>(
      Ob, Wot, bo, nullptr, nullptr, nullptr, nullptr, nullptr, out, 4096, 2048, 2048);
}